// Round 2
// 431.495 us; speedup vs baseline: 1.0016x; 1.0016x over previous
//
#include <hip/hip_runtime.h>
#include <hip/hip_bf16.h>
#include <stdint.h>

#define B 32
#define S 8192
#define D 256
#define H 256

typedef __attribute__((ext_vector_type(8))) short bf16x8;
typedef __attribute__((ext_vector_type(4))) float f32x4;

#define GLOBAL_AS __attribute__((address_space(1)))
#define LDS_AS __attribute__((address_space(3)))

// fp64 pack constants for the single-location arrive+sum protocol:
// contribution = sloc * 2^34 + 2^48.  sloc <= 512 -> data part < 2^47,
// so 15 markers + all data < 16 markers; completion test is val >= 2^52.
// All adds are EXACT in fp64 (addend lsb >= 2^10, total <= 2^52).
#define ZMARK   281474976710656.0      // 2^48
#define ZDONE   4503599627370496.0     // 2^52 = 16 * 2^48
#define ZSCALE  17179869184.0          // 2^34
#define ZINV    5.8207660913467407e-11 // 2^-34

__device__ inline unsigned short f2bf(float f) {
  unsigned u = __float_as_uint(f);
  unsigned r = (u + 0x7FFFu + ((u >> 16) & 1u)) >> 16;
  return (unsigned short)r;
}

__device__ inline unsigned pk2bf(float a, float b) {
  __hip_bfloat162 h = __float22bfloat162_rn(make_float2(a, b));
  unsigned u;
  __builtin_memcpy(&u, &h, 4);
  return u;
}

__device__ inline bf16x8 pack8(float4 a, float4 b) {
  union { unsigned u[4]; bf16x8 v; } c;
  c.u[0] = pk2bf(a.x, a.y);
  c.u[1] = pk2bf(a.z, a.w);
  c.u[2] = pk2bf(b.x, b.y);
  c.u[3] = pk2bf(b.z, b.w);
  return c.v;
}

__device__ inline float fast_tanh(float x) {
  float e = __expf(2.0f * x);
  return 1.0f - 2.0f * __builtin_amdgcn_rcpf(1.0f + e);
}

// ---------------------------------------------------------------------------
// Prep: blocks 0..63 swizzle W_e -> MFMA-B fragment-sequential bf16;
//       blocks 64..95: LSTM cell + dec_proj + b_d + b_e -> combined bias.
//       Block 0 additionally zeroes the per-batch fp64 accumulators used by
//       the fused-softmax protocol (stream order precedes attn).
// ---------------------------------------------------------------------------
__global__ __launch_bounds__(1024) void prep_kernel(
    const float* __restrict__ h0, const float* __restrict__ c0,
    const float* __restrict__ start_token, const float* __restrict__ W_k,
    const float* __restrict__ W_r, const float* __restrict__ b_lstm,
    const float* __restrict__ W_e, const float* __restrict__ W_d,
    const float* __restrict__ b_d, const float* __restrict__ b_e,
    unsigned short* __restrict__ Wfrag, float* __restrict__ decb,
    double* __restrict__ Zd) {
  int blk = blockIdx.x;
  int tid = threadIdx.x;

  __shared__ float xs[D], hs[H], zs[4 * H], hv[H], dpp[4][H];

  if (blk < 64) {
    if (blk == 0 && tid < B) Zd[tid] = 0.0;  // arm the fused-softmax protocol
    // idx = (((nt*8 + kt)*64 + lane)*8 + j); lane holds B[k][n],
    // n = nt*16 + (lane&15), k = kt*32 + (lane>>4)*8 + j
    int gid = blk * 1024 + tid;
    int j = gid & 7;
    int lane = (gid >> 3) & 63;
    int kt = (gid >> 9) & 7;
    int nt = gid >> 12;
    int n = nt * 16 + (lane & 15);
    int k = kt * 32 + (lane >> 4) * 8 + j;
    Wfrag[gid] = f2bf(W_e[k * H + n]);
  } else {
    int b = blk - 64;
    if (tid < D) xs[tid] = start_token[b * D + tid];
    else if (tid < 2 * D) hs[tid - D] = h0[b * H + (tid - D)];
    __syncthreads();
    {
      int jj = tid;
      float a0 = 0.f, a1 = 0.f, a2 = 0.f, a3 = 0.f;
      #pragma unroll 8
      for (int d = 0; d < D; d += 4) {
        a0 += xs[d + 0] * W_k[(d + 0) * 1024 + jj];
        a1 += xs[d + 1] * W_k[(d + 1) * 1024 + jj];
        a2 += xs[d + 2] * W_k[(d + 2) * 1024 + jj];
        a3 += xs[d + 3] * W_k[(d + 3) * 1024 + jj];
      }
      #pragma unroll 8
      for (int h = 0; h < H; h += 4) {
        a0 += hs[h + 0] * W_r[(h + 0) * 1024 + jj];
        a1 += hs[h + 1] * W_r[(h + 1) * 1024 + jj];
        a2 += hs[h + 2] * W_r[(h + 2) * 1024 + jj];
        a3 += hs[h + 3] * W_r[(h + 3) * 1024 + jj];
      }
      zs[jj] = b_lstm[jj] + ((a0 + a1) + (a2 + a3));
    }
    __syncthreads();
    if (tid < H) {
      float zi = zs[tid], zf = zs[H + tid], zg = zs[2 * H + tid], zo = zs[3 * H + tid];
      float si = 1.0f / (1.0f + expf(-zi));
      float sf = 1.0f / (1.0f + expf(-zf));
      float so = 1.0f / (1.0f + expf(-zo));
      float c = sf * c0[b * H + tid] + si * tanhf(zg);
      hv[tid] = so * tanhf(c);
    }
    __syncthreads();
    {
      int hcol = tid & (H - 1);
      int q = tid >> 8;
      float a = 0.f;
      #pragma unroll 8
      for (int k = q * 64; k < q * 64 + 64; ++k) a += hv[k] * W_d[k * H + hcol];
      dpp[q][hcol] = a;
    }
    __syncthreads();
    if (tid < H)
      decb[b * H + tid] = dpp[0][tid] + dpp[1][tid] + dpp[2][tid] + dpp[3][tid]
                        + b_d[tid] + b_e[tid];
  }
}

// ---------------------------------------------------------------------------
// Main: 512 persistent blocks x 16 tiles of 32 rows. Double-buffered LDS
// (2 x 32KB fp32, XOR-swizzled for bank-balanced ds_read_b128), staged via
// async global_load_lds width=16. B fragments live in registers the whole
// kernel. Prefetch issued AFTER the barrier so its vmcnt drain lands at the
// NEXT barrier, a full compute phase later.
//
// Softmax FUSED with a deterministic fixed shift C = sum|v_w| (>= any score,
// since |tanh|<=1; exp(v-C) in [e^-20.5, 1], no under/overflow; computed
// bitwise-identically in every block). Cross-block communication is ONE fp64
// atomicAdd per block into Zd[batch] packing {arrival marker 2^48, sum*2^34}
// — RMW-only, so no relaxed data loads can hit stale per-XCD L2 lines.
// Blocks poll with atomicAdd(+0.0) (a coherent RMW read) until 16 markers.
// Co-residency guaranteed: 512 blocks = exactly 2/CU x 256 CUs
// (launch_bounds(256,2), ~72KB LDS <= 80KB).
// ---------------------------------------------------------------------------
__global__ __launch_bounds__(256, 2) void attn_kernel(
    const float* __restrict__ enc, const unsigned short* __restrict__ Wfrag,
    const float* __restrict__ decb, const float* __restrict__ v_w,
    double* __restrict__ Zd, float* __restrict__ out) {
  __shared__ float Abuf[2][32 * 256];  // exactly 64 KB
  __shared__ float svalp[512][4];      // per-tile per-wave row partials, 8 KB
  __shared__ float rbuf[8];

  const int tid = threadIdx.x;
  const int wave = tid >> 6, lane = tid & 63;
  const int ml = lane & 15, kg = lane >> 4;
  const int bid = blockIdx.x;            // 512 blocks
  const int batch = bid >> 4;            // 16 blocks per batch
  const long row_blk = (long)bid * 512;  // 16 tiles * 32 rows

  // B fragments: persistent in registers (4 nt x 8 kt x 4 VGPR = 128 VGPRs)
  bf16x8 wfr[4][8];
  #pragma unroll
  for (int q = 0; q < 4; ++q)
    #pragma unroll
    for (int kt = 0; kt < 8; ++kt)
      wfr[q][kt] = *(const bf16x8*)(Wfrag + ((size_t)(((wave * 4 + q) * 8 + kt) * 64 + lane) << 3));

  // Epilogue constants (wave's 64-col slice: n = wave*64 + q*16 + ml)
  float bs[4], vw[4];
  #pragma unroll
  for (int q = 0; q < 4; ++q) {
    int n = wave * 64 + q * 16 + ml;
    bs[q] = decb[batch * 256 + n];
    vw[q] = v_w[n];
  }

  // Deterministic softmax shift C = sum_n |v_w[n]|  (each n appears in 4
  // lanes of its wave -> wave sum = 4x slice sum; identical reduce order in
  // every block -> bitwise-equal C across the batch's 16 blocks).
  float Cshift;
  {
    float cs = (fabsf(vw[0]) + fabsf(vw[1])) + (fabsf(vw[2]) + fabsf(vw[3]));
    #pragma unroll
    for (int d = 1; d < 64; d <<= 1) cs += __shfl_xor(cs, d, 64);
    if (lane == 0) rbuf[wave] = cs;
    __syncthreads();
    Cshift = ((rbuf[0] + rbuf[1]) + (rbuf[2] + rbuf[3])) * 0.25f;
  }

  // Async stage of tile t into Abuf[sel]: slot(row,c) = row*64 + (c^(row&7)),
  // LDS dest = uniform base + lane*16 (HW rule); chunk c = lane^(row&7) makes
  // each wave cover one contiguous 1KB row -> fully coalesced.
  auto stage = [&](int t, int sel) {
    const float* gtile = enc + (row_blk + (long)t * 32) * D;
    #pragma unroll
    for (int is = 0; is < 8; ++is) {
      int row = is * 4 + wave;
      int c = lane ^ (row & 7);
      const float* gp = gtile + row * D + c * 4;
      float* lp = &Abuf[sel][(is * 256 + wave * 64) * 4];
      __builtin_amdgcn_global_load_lds((const GLOBAL_AS void*)gp,
                                       (LDS_AS void*)lp, 16, 0, 0);
    }
  };

  stage(0, 0);

  #pragma unroll 2
  for (int t = 0; t < 16; ++t) {
    __syncthreads();  // tile t resident; prefetch t+1 drains at NEXT barrier
    if (t + 1 < 16) stage(t + 1, (t + 1) & 1);

    const float* Ab = Abuf[t & 1];
    f32x4 acc[2][4];
    #pragma unroll
    for (int i = 0; i < 2; ++i)
      #pragma unroll
      for (int q = 0; q < 4; ++q) acc[i][q] = (f32x4){0.f, 0.f, 0.f, 0.f};

    #pragma unroll
    for (int kt = 0; kt < 8; ++kt) {
      #pragma unroll
      for (int i = 0; i < 2; ++i) {
        int row = i * 16 + ml;
        int x = ml & 7;
        int c0 = kt * 8 + kg * 2;
        float4 v0 = *(const float4*)&Ab[(row * 64 + (c0 ^ x)) * 4];
        float4 v1 = *(const float4*)&Ab[(row * 64 + ((c0 + 1) ^ x)) * 4];
        bf16x8 af = pack8(v0, v1);
        #pragma unroll
        for (int q = 0; q < 4; ++q)
          acc[i][q] = __builtin_amdgcn_mfma_f32_16x16x32_bf16(af, wfr[q][kt], acc[i][q], 0, 0, 0);
      }
    }

    // Epilogue: tanh(acc + bias[n]) * v_w; partial over this wave's 64 cols
    float part[8];
    #pragma unroll
    for (int v = 0; v < 8; ++v) part[v] = 0.f;
    #pragma unroll
    for (int q = 0; q < 4; ++q)
      #pragma unroll
      for (int i = 0; i < 2; ++i)
        #pragma unroll
        for (int r = 0; r < 4; ++r)
          part[i * 4 + r] += fast_tanh(acc[i][q][r] + bs[q]) * vw[q];
    // reduce over the 16 column-lanes (lane bits 0..3)
    #pragma unroll
    for (int m = 1; m < 16; m <<= 1)
      #pragma unroll
      for (int v = 0; v < 8; ++v) part[v] += __shfl_xor(part[v], m, 64);
    if (ml == 0) {
      int lr0 = t * 32 + kg * 4;  // local row = kg*4 + r (+ i*16)
      #pragma unroll
      for (int i = 0; i < 2; ++i)
        #pragma unroll
        for (int r = 0; r < 4; ++r)
          svalp[lr0 + i * 16 + r][wave] = part[i * 4 + r];
    }
  }

  // ---- Fused softmax (fixed shift; RMW-only cross-block protocol) ----
  __syncthreads();  // last tile's svalp writes visible

  // Each thread owns rows 2*tid, 2*tid+1; sum the 4 wave partials.
  float4 pa = *(const float4*)&svalp[2 * tid][0];
  float4 pb = *(const float4*)&svalp[2 * tid + 1][0];
  float va = (pa.x + pa.y) + (pa.z + pa.w);
  float vb = (pb.x + pb.y) + (pb.z + pb.w);

  float ea = __expf(va - Cshift);
  float eb = __expf(vb - Cshift);

  // Block-local sum of exp
  float s = ea + eb;
  #pragma unroll
  for (int d = 1; d < 64; d <<= 1) s += __shfl_xor(s, d, 64);
  if (lane == 0) rbuf[wave] = s;
  __syncthreads();

  if (tid == 0) {
    float sloc = (rbuf[0] + rbuf[1]) + (rbuf[2] + rbuf[3]);
    double contrib = (double)sloc * ZSCALE + ZMARK;
    atomicAdd(&Zd[batch], contrib);
    double v = atomicAdd(&Zd[batch], 0.0);  // coherent RMW read
    while (v < ZDONE) {
      __builtin_amdgcn_s_sleep(8);
      v = atomicAdd(&Zd[batch], 0.0);
    }
    float Z = (float)((v - ZDONE) * ZINV);
    rbuf[4] = 1.0f / Z;
  }
  __syncthreads();

  float inv = rbuf[4];
  float2 o2 = make_float2(ea * inv, eb * inv);
  *(float2*)&out[row_blk + 2 * tid] = o2;
}

extern "C" void kernel_launch(void* const* d_in, const int* in_sizes, int n_in,
                              void* d_out, int out_size, void* d_ws, size_t ws_size,
                              hipStream_t stream) {
  const float* enc         = (const float*)d_in[0];
  const float* h0          = (const float*)d_in[1];
  const float* c0          = (const float*)d_in[2];
  const float* start_token = (const float*)d_in[3];
  const float* W_k         = (const float*)d_in[4];
  const float* W_r         = (const float*)d_in[5];
  const float* b_lstm      = (const float*)d_in[6];
  const float* W_e         = (const float*)d_in[7];
  const float* b_e         = (const float*)d_in[8];
  const float* W_d         = (const float*)d_in[9];
  const float* b_d         = (const float*)d_in[10];
  const float* v_w         = (const float*)d_in[11];
  // d_in[12] = v_b: softmax(s + c) == softmax(s), cancels exactly.
  float* out = (float*)d_out;

  char* wsb = (char*)d_ws;
  unsigned short* Wfrag = (unsigned short*)wsb;                 // 128 KB
  float* decb           = (float*)(wsb + 131072);               // 32 KB
  double* Zd            = (double*)(wsb + 131072 + 32768);      // 256 B

  prep_kernel<<<96, 1024, 0, stream>>>(h0, c0, start_token, W_k, W_r, b_lstm,
                                       W_e, W_d, b_d, b_e, Wfrag, decb, Zd);
  attn_kernel<<<512, 256, 0, stream>>>(enc, Wfrag, decb, v_w, Zd, out);
}